// Round 16
// baseline (198.415 us; speedup 1.0000x reference)
//
#include <hip/hip_runtime.h>
#include <hip/hip_bf16.h>

// ---------------------------------------------------------------------------
// Causal MHA. B=2, S=2048, D=1024, H=16, Dh=64. Inputs fp32, output fp32.
// Internal bf16 MFMA.
// Memory plan (ws 24 MB, d_out 16 MB):
//   d_out[0:8MB]   Q   packed frags bf16   d_out[8:16MB]  xb (4096,1024) bf16
//   ws[0:8MB]      K   packed frags bf16
//   ws[8:16MB]     V   packed frags bf16
//   ws[16:24MB]    Wq/Wk/Wv bf16 (6MB) + rope table (512KB) during qkv,
//                  then ATT (B,S,D) bf16 overwrites
// R29: r27 landed (191.5us; attn 51.4, VGPR 124, occ 18.5% = 4-block cap).
// attn register diet via PHASE SPLIT: each 64-key tile processed as two
// sequential 32-key phases. PV pairing decomposes cleanly (kc0-1 <- s0's
// P,V; kc2-3 <- s1's), halving live sc/pw/rsp/vf (~-36 arch regs; target
// VGPR <=102 = 5 waves/SIMD). Fully-masked s1 phases on diagonal tiles are
// now skipped (old code ran 8 PV MFMAs on zeros). Merge -> 2-group scheme
// (Obuf[2][64][33], waves 0-1 write / 2-3 add): LDS 34.8->17.9KB so LDS no
// longer caps at 4 blocks either. Same online-softmax math at 32-key
// granularity. qkv/out_gemm/prep byte-identical to R27.
// ---------------------------------------------------------------------------

typedef __bf16 bf16x8 __attribute__((ext_vector_type(8)));
typedef float floatx4 __attribute__((ext_vector_type(4)));
typedef float floatx16 __attribute__((ext_vector_type(16)));
typedef int intx2 __attribute__((ext_vector_type(2)));

#define MFMA16(A, B, C) __builtin_amdgcn_mfma_f32_16x16x32_bf16((A), (B), (C), 0, 0, 0)
#define MFMA32(A, B, C) __builtin_amdgcn_mfma_f32_32x32x16_bf16((A), (B), (C), 0, 0, 0)

#define S_LEN 2048
#define D_MODEL 1024
#define NHEAD 16
#define DHEAD 64
#define NTOK 4096
#define NEG_SENTINEL (-1.0e30f)
// 0.125 (1/sqrt(Dh)) * log2(e): scores leave QKV pre-scaled for exp2-softmax
#define QSCALE_LOG2E 0.18033688011112042f

__device__ __forceinline__ short b16(float f) {
  __bf16 h = (__bf16)f;
  union { __bf16 b; short s; } u; u.b = h;
  return u.s;
}
// pack two floats into one u32 of 2 bf16 (compiler emits v_cvt_pk_bf16_f32)
__device__ __forceinline__ unsigned pk2(float x, float y) {
  union { __bf16 b[2]; unsigned u; } t;
  t.b[0] = (__bf16)x; t.b[1] = (__bf16)y;
  return t.u;
}
__device__ __forceinline__ bf16x8 ld_frag(const short* p) {
  return *(const bf16x8*)p;
}
// async global->LDS, 16B per lane; LDS dest = wave-uniform base + lane*16.
__device__ __forceinline__ void gl2lds16(const short* g, short* l) {
  __builtin_amdgcn_global_load_lds(
      (const __attribute__((address_space(1))) unsigned int*)g,
      (__attribute__((address_space(3))) unsigned int*)l, 16, 0, 0);
}
__device__ __forceinline__ float max3f(float a, float b, float c) {
  return fmaxf(fmaxf(a, b), c);   // clang fuses to v_max3_f32
}

// ---------------------------------------------------------------------------
// Prep: y=0..3 convert x/Wq/Wk/Wv to bf16; y=4 builds the RoPE table
// tab[s*32+p] = (cos, sin)(s * 10000^(-p/32)).  grid (256,5) x 256.
// ---------------------------------------------------------------------------
__global__ __launch_bounds__(256) void prep_kernel(
    const float* __restrict__ x, const float* __restrict__ wq,
    const float* __restrict__ wk, const float* __restrict__ wv,
    short* __restrict__ xb, short* __restrict__ wqb,
    short* __restrict__ wkb, short* __restrict__ wvb,
    float2* __restrict__ tab) {
  const int y = blockIdx.y;
  if (y == 4) {
    int i = blockIdx.x * 256 + threadIdx.x;  // 65536 = 2048*32 exactly
    int s = i >> 5, p = i & 31;
    float inv_freq = __expf(-0.28782313662425575f * (float)p);
    float ang = (float)s * inv_freq;
    float sn, c;
    sincosf(ang, &sn, &c);  // accurate; one-time cost
    tab[i] = make_float2(c, sn);
    return;
  }
  const float* src = (y == 0) ? x : (y == 1) ? wq : (y == 2) ? wk : wv;
  short* dst = (y == 0) ? xb : (y == 1) ? wqb : (y == 2) ? wkb : wvb;
  const int n4 = ((y == 0) ? NTOK * D_MODEL : D_MODEL * D_MODEL) >> 2;
  for (int i = blockIdx.x * 256 + threadIdx.x; i < n4; i += gridDim.x * 256) {
    float4 v = ((const float4*)src)[i];
    short4 o;
    o.x = b16(v.x); o.y = b16(v.y); o.z = b16(v.z); o.w = b16(v.w);
    ((short4*)dst)[i] = o;
  }
}

// ---------------------------------------------------------------------------
// QKV + RoPE (unchanged from R24): LDS-staged 128x128 tile, BK=64, T2 XOR
// swizzle paired for global_load_lds. Epilogue: fragment-packed Q/K/V.
// ---------------------------------------------------------------------------
__global__ __launch_bounds__(256) void qkv_rope_kernel(
    const short* __restrict__ xb,
    const short* __restrict__ Wqb, const short* __restrict__ Wkb,
    const short* __restrict__ Wvb,
    const float2* __restrict__ ropetab,
    short* __restrict__ qws, short* __restrict__ kws, short* __restrict__ vtws) {
  __shared__ __align__(16) short SM[4 * 64 * 72];  // 36KB; staging uses 32KB
  short* As = SM;              // [128][64] bf16, swizzled units
  short* Bs = SM + 128 * 64;

  const int tid = threadIdx.x;
  const int lane = tid & 63;
  const int wv = tid >> 6;
  const int col = lane & 15, quad = lane >> 4;
  const int half = lane >> 5, l31 = lane & 31;
  const int wr = wv >> 1, wc = wv & 1;
  const int gemm = blockIdx.y;
  const int bm = blockIdx.x >> 3;
  const int bn = blockIdx.x & 7;
  const short* W = (gemm == 0) ? Wqb : (gemm == 1) ? Wkb : Wvb;

  const int srow8 = lane >> 3;                    // 0..7
  const int scolsw = ((lane & 7) ^ srow8) * 8;    // swizzled source col
  const short* gAa[4]; short* lAa[4];
  const short* gBa[4]; short* lBa[4];
#pragma unroll
  for (int g = 0; g < 2; ++g)
#pragma unroll
    for (int j = 0; j < 2; ++j) {
      const int idx = g * 2 + j;
      const int r0 = g * 64 + wv * 16 + j * 8;
      gAa[idx] = xb + (size_t)(bm * 128 + r0 + srow8) * D_MODEL + scolsw;
      lAa[idx] = As + r0 * 64;
      gBa[idx] = W + (size_t)(bn * 128 + r0 + srow8) * D_MODEL + scolsw;
      lBa[idx] = Bs + r0 * 64;
    }

  floatx4 acc[4][4];
#pragma unroll
  for (int i = 0; i < 4; ++i)
#pragma unroll
    for (int j = 0; j < 4; ++j) acc[i][j] = (floatx4){0.f, 0.f, 0.f, 0.f};

  const int arow = wr * 64;  // this wave's A row base (mult of 8)
  const int brow = wc * 64;

  for (int k0 = 0; k0 < D_MODEL; k0 += 64) {
    __syncthreads();
#pragma unroll
    for (int i = 0; i < 4; ++i) gl2lds16(gAa[i] + k0, lAa[i]);
#pragma unroll
    for (int i = 0; i < 4; ++i) gl2lds16(gBa[i] + k0, lBa[i]);
    __syncthreads();
#pragma unroll
    for (int kk = 0; kk < 2; ++kk) {
      bf16x8 a[4], b[4];
      const int usel = (kk * 4 + quad) ^ (col & 7);  // swizzled 16B unit
#pragma unroll
      for (int mt = 0; mt < 4; ++mt)
        a[mt] = ld_frag(&As[(arow + mt * 16 + col) * 64 + usel * 8]);
#pragma unroll
      for (int nt = 0; nt < 4; ++nt)
        b[nt] = ld_frag(&Bs[(brow + nt * 16 + col) * 64 + usel * 8]);
#pragma unroll
      for (int mt = 0; mt < 4; ++mt)
#pragma unroll
        for (int nt = 0; nt < 4; ++nt)
          acc[mt][nt] = MFMA16(a[mt], b[nt], acc[mt][nt]);
    }
  }
  __syncthreads();  // staging region about to be reused as epilogue buffer

  // ---- epilogue (per-wave 64x64 tile) -------------------------------------
  const int tm = bm * 2 + wr;   // 0..63
  const int tn = bn * 2 + wc;   // 0..15 (= head)
  short* Ep = &SM[wv * 64 * 72];
  const int mbase = tm * 64;
  const int bb = mbase >> 11;
  const int s0 = mbase & (S_LEN - 1);

  if (gemm == 2) {
    // Ep[d][s] (d = nl 0..63, s = ml 0..63), stride 72
#pragma unroll
    for (int mt = 0; mt < 4; ++mt)
#pragma unroll
      for (int nt = 0; nt < 4; ++nt) {
        int nl = nt * 16 + col;
#pragma unroll
        for (int r = 0; r < 4; ++r)
          Ep[nl * 72 + mt * 16 + quad * 4 + r] = b16(acc[mt][nt][r]);
      }
    // fragment-packed V store: lane l <-> [d = dt*32+l31][keys kc*16+half*8..]
    short* vb2 = vtws + (size_t)(bb * NHEAD + tn) * S_LEN * DHEAD;
    const int vtile = s0 >> 6;  // 64-key tile index (0..31)
#pragma unroll
    for (int dt = 0; dt < 2; ++dt) {
      const int4* src = (const int4*)&Ep[(dt * 32 + l31) * 72];
      int4* dst = (int4*)(vb2 + (size_t)(vtile * 8 + dt) * 512);
#pragma unroll
      for (int kc = 0; kc < 4; ++kc)
        dst[kc * 2 * 64 + lane] = src[kc * 2 + half];
    }
  } else {
    short* outp = (gemm == 0) ? qws : kws;
    const float qscale = (gemm == 0) ? QSCALE_LOG2E : 1.0f;
    // Ep[token][d] (token = ml 0..63, d = nl 0..63), stride 72
#pragma unroll
    for (int nt = 0; nt < 4; ++nt) {
      int nl = nt * 16 + col;
      const float2* tp = ropetab + (nl >> 1);
#pragma unroll
      for (int mt = 0; mt < 4; ++mt)
#pragma unroll
        for (int r = 0; r < 4; ++r) {
          int ml = mt * 16 + quad * 4 + r;
          float2 cs = tp[(size_t)(s0 + ml) * 32];
          float val = acc[mt][nt][r];
          float partner = __shfl_xor(val, 1);
          float o = ((nl & 1) == 0) ? (val * cs.x - partner * cs.y)
                                    : (partner * cs.y + val * cs.x);
          Ep[ml * 72 + nl] = b16(o * qscale);
        }
    }
    // fragment-packed Q/K store: lane l <-> [token = g2*32+l31][d kc*16+half*8..]
    short* ob2 = outp + (size_t)(bb * NHEAD + tn) * S_LEN * DHEAD;
    const int kgrp0 = s0 >> 5;  // 32-token group index (0..63)
#pragma unroll
    for (int g2 = 0; g2 < 2; ++g2) {
      const int4* src = (const int4*)&Ep[(g2 * 32 + l31) * 72];
      int4* dst = (int4*)(ob2 + (size_t)((kgrp0 + g2) * 4) * 512);
#pragma unroll
      for (int kc = 0; kc < 4; ++kc)
        dst[kc * 64 + lane] = src[kc * 2 + half];
    }
  }
}

// ---------------------------------------------------------------------------
// Split-K flash attention, R29: 32-key PHASE SPLIT of the R27 core.
// Each 64-key tile = phase0 (keys kt..kt+31, always valid) then phase1
// (keys kt+32.., skipped entirely when causally invalid). Halves live
// sc/pw/rsp/vf; PV decomposes cleanly (kc0-1 <- phase0, kc2-3 <- phase1).
// Merge: 2-group (waves 0-1 write, 2-3 add). grid 2048 x 256.
// ---------------------------------------------------------------------------
__global__ __launch_bounds__(256) void attn_kernel(
    const short* __restrict__ qws, const short* __restrict__ kws,
    const short* __restrict__ vtws, short* __restrict__ att) {
  const int tid = threadIdx.x;
  const int wv = tid >> 6;
  const int lane = tid & 63;
  const int half = lane >> 5, l31 = lane & 31;
  const int bh = blockIdx.x & 31;          // consecutive blocks -> different
  const int b = bh >> 4, h = bh & 15;      // (b,h): same (b,h) lands on the
  const int qt = 63 - (blockIdx.x >> 5);   // same XCD; big tiles first
  const int q0 = qt * 32;

  __shared__ float ml[2][4][32];      // [0]=m, [1]=l  per wave per q (1KB)
  __shared__ float Obuf[2][64][33];   // 2-group O^T partials (16.9KB)

  const short* qbase = qws + (size_t)(b * NHEAD + h) * S_LEN * DHEAD;
  const short* kbase = kws + (size_t)(b * NHEAD + h) * S_LEN * DHEAD;
  const short* vbase = vtws + (size_t)(b * NHEAD + h) * S_LEN * DHEAD;

  bf16x8 qf[4];
#pragma unroll
  for (int kc = 0; kc < 4; ++kc)
    qf[kc] = ld_frag(qbase + (size_t)(qt * 4 + kc) * 512 + lane * 8);

  float m_i = NEG_SENTINEL, l_i = 0.f;   // log2-domain running max / sum
  floatx16 ot[2] = {};  // O^T: d = dt*32+(rg&3)+8*(rg>>2)+4*half, q = l31

  const int nit = (q0 + 32 + 63) >> 6;  // total 64-key tiles

  bf16x8 kfA[2][4];  // single K buffer; per-s in-place prefetch after QK^T
  auto loadKs = [&](int s, int tkt) {
    if (tkt + s * 32 <= q0 + 31) {  // wave-uniform validity
      const short* kr = kbase + (size_t)(((tkt >> 5) + s) * 4) * 512 + lane * 8;
#pragma unroll
      for (int kc = 0; kc < 4; ++kc) kfA[s][kc] = ld_frag(kr + kc * 512);
    }
  };

  // one 32-key phase: scores (16/lane), mask, softmax, 4 PV MFMAs.
  auto phase = [&](floatx16 sc, int kbase_rel, const short* vr) {
    // vr points at this phase's V frags: (kcg*2+dt)*512 for kcg in {0,1}
    bf16x8 vfp[2][2];
#pragma unroll
    for (int kcg = 0; kcg < 2; ++kcg)
#pragma unroll
      for (int dt = 0; dt < 2; ++dt)
        vfp[kcg][dt] = ld_frag(vr + (size_t)(kcg * 2 + dt) * 512);
    // per-half row max: 5 max3 triples + 1, depth ~3
    const float* sf = (const float*)&sc;
    float u0 = max3f(sf[0], sf[1], sf[2]);
    float u1 = max3f(sf[3], sf[4], sf[5]);
    float u2 = max3f(sf[6], sf[7], sf[8]);
    float u3 = max3f(sf[9], sf[10], sf[11]);
    float u4 = max3f(sf[12], sf[13], sf[14]);
    float rm = fmaxf(max3f(u0, u1, u2), max3f(u3, u4, sf[15]));
    // defer-max: cross-half shuffle only when a rescale is needed
    if (!__all(rm <= m_i + 8.0f)) {
      float rmf = fmaxf(rm, __shfl_xor(rm, 32));
      float mnew = fmaxf(m_i, rmf);
      float alpha = exp2f(m_i - mnew);
      m_i = mnew;
      l_i *= alpha;
#pragma unroll
      for (int dt = 0; dt < 2; ++dt)
#pragma unroll
        for (int rg = 0; rg < 16; ++rg) ot[dt][rg] *= alpha;
    }
    // P = exp2(S - m), packed to bf16 pairs in registers
    unsigned pw[4][2];
    float rsp[4];
#pragma unroll
    for (int g = 0; g < 4; ++g) {
      float p0 = exp2f(sc[4 * g + 0] - m_i);
      float p1 = exp2f(sc[4 * g + 1] - m_i);
      float p2 = exp2f(sc[4 * g + 2] - m_i);
      float p3 = exp2f(sc[4 * g + 3] - m_i);
      rsp[g] = (p0 + p1) + (p2 + p3);
      pw[g][0] = pk2(p0, p1);
      pw[g][1] = pk2(p2, p3);
    }
    float rs = (rsp[0] + rsp[1]) + (rsp[2] + rsp[3]);
    rs += __shfl_xor(rs, 32);
    l_i += rs;
    // PV: permlane32_swap assembles B-fragments in-register
#pragma unroll
    for (int kcg = 0; kcg < 2; ++kcg) {
      intx2 s01 = __builtin_amdgcn_permlane32_swap(
          (int)pw[2 * kcg][0], (int)pw[2 * kcg + 1][0], false, false);
      intx2 s23 = __builtin_amdgcn_permlane32_swap(
          (int)pw[2 * kcg][1], (int)pw[2 * kcg + 1][1], false, false);
      union { unsigned u[4]; bf16x8 f; } fr;
      fr.u[0] = (unsigned)s01[0]; fr.u[1] = (unsigned)s23[0];
      fr.u[2] = (unsigned)s01[1]; fr.u[3] = (unsigned)s23[1];
#pragma unroll
      for (int dt = 0; dt < 2; ++dt)
        ot[dt] = MFMA32(vfp[kcg][dt], fr.f, ot[dt]);
    }
    (void)kbase_rel;
  };

  int it = wv;
  if (it < nit) { loadKs(0, it * 64); loadKs(1, it * 64); }  // prologue

  for (; it < nit; it += 4) {
    const int kt = it * 64;
    const bool havenext = (it + 4 < nit);
    const short* vr0 = vbase + (size_t)(kt >> 6) * 8 * 512 + lane * 8;

    // ---- phase 0: keys kt..kt+31 (always causally reachable) ----
    {
      floatx16 a = {};
#pragma unroll
      for (int kc = 0; kc < 4; ++kc) a = MFMA32(kfA[0][kc], qf[kc], a);
      if (havenext) loadKs(0, (it + 4) * 64);   // kfA[0] dead now
      if (kt + 31 > q0) {
        const int lim = q0 + l31 - kt;
#pragma unroll
        for (int rg = 0; rg < 16; ++rg) {
          int rel = (rg & 3) + 8 * (rg >> 2) + 4 * half;
          if (rel > lim) a[rg] = NEG_SENTINEL;
        }
      }
      phase(a, kt, vr0);
    }

    // ---- phase 1: keys kt+32..kt+63 (skip entirely when invalid) ----
    if (kt + 32 <= q0 + 31) {
      floatx16 a = {};
#pragma unroll
      for (int kc = 0; kc < 4; ++kc) a = MFMA32(kfA[1][kc], qf[kc], a);
      if (havenext) loadKs(1, (it + 4) * 64);   // kfA[1] dead now
      if (kt + 63 > q0) {
        const int lim = q0 + l31 - kt;
#pragma unroll
        for (int rg = 0; rg < 16; ++rg) {
          int rel = 32 + (rg & 3) + 8 * (rg >> 2) + 4 * half;
          if (rel > lim) a[rg] = NEG_SENTINEL;
        }
      }
      phase(a, kt + 32, vr0 + (size_t)4 * 512);
    }
  }

  // ---- 2-group block merge (log2 domain): 3 barriers ---------------------
  ml[0][wv][l31] = m_i;
  ml[1][wv][l31] = l_i;
  __syncthreads();
  float m0 = ml[0][0][l31], m1 = ml[0][1][l31];
  float m2 = ml[0][2][l31], m3 = ml[0][3][l31];
  float mtot = fmaxf(fmaxf(m0, m1), fmaxf(m2, m3));
  float sw = exp2f(m_i - mtot);  // idle wave: 0

  if (wv < 2) {
#pragma unroll
    for (int dt = 0; dt < 2; ++dt)
#pragma unroll
      for (int rg = 0; rg < 16; ++rg) {
        int d = dt * 32 + (rg & 3) + 8 * (rg >> 2) + 4 * half;
        Obuf[wv][d][l31] = ot[dt][rg] * sw;
      }
  }
  __syncthreads();
  if (wv >= 2) {
#pragma unroll
    for (int dt = 0; dt < 2; ++dt)
#pragma unroll
      for (int rg = 0; rg < 16; ++rg) {
        int d = dt * 32 + (rg & 3) + 8 * (rg >> 2) + 4 * half;
        Obuf[wv - 2][d][l31] += ot[dt][rg] * sw;
      }
  }
  __syncthreads();

  // ---- final normalize + coalesced store (128B per q-row) ---------------
  const int q = tid >> 3;            // 0..31
  const int d0 = (tid & 7) * 8;      // 0,8,..,56
  float mm0 = ml[0][0][q], mm1 = ml[0][1][q], mm2 = ml[0][2][q], mm3 = ml[0][3][q];
  float mt2 = fmaxf(fmaxf(mm0, mm1), fmaxf(mm2, mm3));
  float lt = ml[1][0][q] * exp2f(mm0 - mt2) + ml[1][1][q] * exp2f(mm1 - mt2) +
             ml[1][2][q] * exp2f(mm2 - mt2) + ml[1][3][q] * exp2f(mm3 - mt2);
  float inv = 1.0f / lt;  // lt >= 1
  union { bf16x8 hh; int4 i4; } cv;
#pragma unroll
  for (int i = 0; i < 8; ++i) {
    float v = Obuf[0][d0 + i][q] + Obuf[1][d0 + i][q];
    cv.hh[i] = (__bf16)(v * inv);
  }
  int4* dst = (int4*)(att + (size_t)(b * S_LEN + q0 + q) * D_MODEL + h * DHEAD + d0);
  *dst = cv.i4;
}

// ---------------------------------------------------------------------------
// Output projection (unchanged from R26): BK=64, T2 XOR swizzle; A via
// global_load_lds w/ inverse-permuted source; B (fp32 Wo) reg-staged with
// swizzled ds_write. 128x64 tiles, 512 blocks = 2 blocks/CU.
// ---------------------------------------------------------------------------
__global__ __launch_bounds__(256) void out_gemm_kernel(
    const short* __restrict__ att, const float* __restrict__ Wo,
    float* __restrict__ out) {
  __shared__ __align__(16) short As[128 * 64];  // 16KB, swizzled units
  __shared__ __align__(16) short Bs[64 * 64];   // 8KB, swizzled units

  const int tid = threadIdx.x;
  const int lane = tid & 63;
  const int wv = tid >> 6;
  const int col = lane & 15, quad = lane >> 4;
  const int wr = wv >> 1, wc = wv & 1;
  const int bm = blockIdx.x >> 4;   // 32 M-tiles of 128
  const int bn = blockIdx.x & 15;   // 16 N-tiles of 64

  const int srow8 = lane >> 3;
  const int scolsw = ((lane & 7) ^ srow8) * 8;    // swizzled source col
  const short* gAa[4]; short* lAa[4];
#pragma unroll
  for (int g = 0; g < 2; ++g)
#pragma unroll
    for (int j = 0; j < 2; ++j) {
      const int idx = g * 2 + j;
      const int r0 = g * 64 + wv * 16 + j * 8;
      gAa[idx] = att + (size_t)(bm * 128 + r0 + srow8) * D_MODEL + scolsw;
      lAa[idx] = As + r0 * 64;
    }

  const int browB = tid >> 2;
  const int bc0 = (tid & 3) * 16;
  const float* gBf = Wo + (size_t)(bn * 64 + browB) * D_MODEL + bc0;
  short* lBw0 = Bs + browB * 64 + (((tid & 3) * 2) ^ (browB & 7)) * 8;
  short* lBw1 = Bs + browB * 64 + (((tid & 3) * 2 + 1) ^ (browB & 7)) * 8;

  floatx4 acc[4][2];
#pragma unroll
  for (int i = 0; i < 4; ++i)
#pragma unroll
    for (int j = 0; j < 2; ++j) acc[i][j] = (floatx4){0.f, 0.f, 0.f, 0.f};

  const int arow = wr * 64;
  const int brow = wc * 32;

  for (int k0 = 0; k0 < D_MODEL; k0 += 64) {
    float4 w0 = *(const float4*)(gBf + k0);
    float4 w1 = *(const float4*)(gBf + k0 + 4);
    float4 w2 = *(const float4*)(gBf + k0 + 8);
    float4 w3 = *(const float4*)(gBf + k0 + 12);
    __syncthreads();  // prev iteration's LDS reads drained
#pragma unroll
    for (int i = 0; i < 4; ++i) gl2lds16(gAa[i] + k0, lAa[i]);
    union { unsigned u[4]; int4 i4; } b0, b1;
    b0.u[0] = pk2(w0.x, w0.y); b0.u[1] = pk2(w0.z, w0.w);
    b0.u[2] = pk2(w1.x, w1.y); b0.u[3] = pk2(w1.z, w1.w);
    b1.u[0] = pk2(w2.x, w2.y); b1.u[1] = pk2(w2.z, w2.w);
    b1.u[2] = pk2(w3.x, w3.y); b1.u[3] = pk2(w3.z, w3.w);
    *(int4*)lBw0 = b0.i4;
    *(int4*)lBw1 = b1.i4;
    __syncthreads();  // tile resident (vmcnt for gl2lds16, lgkm for ds_write)
#pragma unroll
    for (int kk = 0; kk < 2; ++kk) {
      bf16x8 a[4], b[2];
      const int usel = (kk * 4 + quad) ^ (col & 7);  // swizzled 16B unit
#pragma unroll
      for (int mt = 0; mt < 4; ++mt)
        a[mt] = ld_frag(&As[(arow + mt * 16 + col) * 64 + usel * 8]);
#pragma unroll
      for (int nt = 0; nt < 2; ++nt)
        b[nt] = ld_frag(&Bs[(brow + nt * 16 + col) * 64 + usel * 8]);
#pragma unroll
      for (int mt = 0; mt < 4; ++mt)
#pragma unroll
        for (int nt = 0; nt < 2; ++nt)
          acc[mt][nt] = MFMA16(a[mt], b[nt], acc[mt][nt]);
    }
  }

#pragma unroll
  for (int mt = 0; mt < 4; ++mt)
#pragma unroll
    for (int nt = 0; nt < 2; ++nt) {
      int n = bn * 64 + wc * 32 + nt * 16 + col;
#pragma unroll
      for (int r = 0; r < 4; ++r) {
        int m = bm * 128 + wr * 64 + mt * 16 + quad * 4 + r;
        out[(size_t)m * D_MODEL + n] = acc[mt][nt][r];
      }
    }
}

// ---------------------------------------------------------------------------
extern "C" void kernel_launch(void* const* d_in, const int* in_sizes, int n_in,
                              void* d_out, int out_size, void* d_ws, size_t ws_size,
                              hipStream_t stream) {
  const float* x  = (const float*)d_in[0];
  const float* Wq = (const float*)d_in[2];
  const float* Wk = (const float*)d_in[3];
  const float* Wv = (const float*)d_in[4];
  const float* Wo = (const float*)d_in[5];
  float* out = (float*)d_out;

  const size_t TENS = (size_t)NTOK * D_MODEL;
  const size_t WELEM = (size_t)D_MODEL * D_MODEL;

  short* qws  = (short*)d_out;
  short* xb   = (short*)d_out + TENS;
  short* kws  = (short*)d_ws;
  short* vtws = kws + TENS;
  short* attws = vtws + TENS;
  short* wqb = attws;
  short* wkb = wqb + WELEM;
  short* wvb = wkb + WELEM;
  float2* ropetab = (float2*)(wvb + WELEM);

  prep_kernel<<<dim3(256, 5), 256, 0, stream>>>(x, Wq, Wk, Wv, xb, wqb, wkb, wvb, ropetab);
  qkv_rope_kernel<<<dim3(256, 3), 256, 0, stream>>>(xb, wqb, wkb, wvb, ropetab, qws, kws, vtws);
  attn_kernel<<<dim3(2048), 256, 0, stream>>>(qws, kws, vtws, attws);
  out_gemm_kernel<<<dim3(512), 256, 0, stream>>>(attws, Wo, out);
}

// Round 17
// 191.041 us; speedup vs baseline: 1.0386x; 1.0386x over previous
//
#include <hip/hip_runtime.h>
#include <hip/hip_bf16.h>

// ---------------------------------------------------------------------------
// Causal MHA. B=2, S=2048, D=1024, H=16, Dh=64. Inputs fp32, output fp32.
// Internal bf16 MFMA.
// Memory plan (ws 24 MB, d_out 16 MB):
//   d_out[0:8MB]   Q   packed frags bf16   d_out[8:16MB]  xb (4096,1024) bf16
//   ws[0:8MB]      K   packed frags bf16
//   ws[8:16MB]     V   packed frags bf16
//   ws[16:24MB]    Wq/Wk/Wv bf16 (6MB) + rope table (512KB) during qkv,
//                  then ATT (B,S,D) bf16 overwrites
// R30 == exact revert to R27 (benched 191.5us). R29 post-mortem: 32-key
// phase split DOUBLED the serial softmax chain count per tile (70.6us,
// MfmaUtil 12.9->9.4%) and missed the register target (120 vs <=102) —
// chain-count-limited loop punishes added sequential phases. Recorded with
// the three pairing failures: no more perturbations of this structure;
// further attn gains require the 8-wave rewrite.
// R27 attn: exp2 softmax, in-reg P via cvt_pk+permlane32_swap, single K
// buffer in-place prefetch, parallel 4-way merge, shuffle-skip defer-max,
// max3 tree. qkv: BK=64 + T2 XOR swizzle. out_gemm: BK=64 swizzled, fused
// Wo conversion. prep: cvt + rope table.
// ---------------------------------------------------------------------------

typedef __bf16 bf16x8 __attribute__((ext_vector_type(8)));
typedef float floatx4 __attribute__((ext_vector_type(4)));
typedef float floatx16 __attribute__((ext_vector_type(16)));
typedef int intx2 __attribute__((ext_vector_type(2)));

#define MFMA16(A, B, C) __builtin_amdgcn_mfma_f32_16x16x32_bf16((A), (B), (C), 0, 0, 0)
#define MFMA32(A, B, C) __builtin_amdgcn_mfma_f32_32x32x16_bf16((A), (B), (C), 0, 0, 0)

#define S_LEN 2048
#define D_MODEL 1024
#define NHEAD 16
#define DHEAD 64
#define NTOK 4096
#define NEG_SENTINEL (-1.0e30f)
// 0.125 (1/sqrt(Dh)) * log2(e): scores leave QKV pre-scaled for exp2-softmax
#define QSCALE_LOG2E 0.18033688011112042f

__device__ __forceinline__ short b16(float f) {
  __bf16 h = (__bf16)f;
  union { __bf16 b; short s; } u; u.b = h;
  return u.s;
}
// pack two floats into one u32 of 2 bf16 (compiler emits v_cvt_pk_bf16_f32)
__device__ __forceinline__ unsigned pk2(float x, float y) {
  union { __bf16 b[2]; unsigned u; } t;
  t.b[0] = (__bf16)x; t.b[1] = (__bf16)y;
  return t.u;
}
__device__ __forceinline__ bf16x8 ld_frag(const short* p) {
  return *(const bf16x8*)p;
}
// async global->LDS, 16B per lane; LDS dest = wave-uniform base + lane*16.
__device__ __forceinline__ void gl2lds16(const short* g, short* l) {
  __builtin_amdgcn_global_load_lds(
      (const __attribute__((address_space(1))) unsigned int*)g,
      (__attribute__((address_space(3))) unsigned int*)l, 16, 0, 0);
}
__device__ __forceinline__ float max3f(float a, float b, float c) {
  return fmaxf(fmaxf(a, b), c);   // clang fuses to v_max3_f32
}

// ---------------------------------------------------------------------------
// Prep: y=0..3 convert x/Wq/Wk/Wv to bf16; y=4 builds the RoPE table
// tab[s*32+p] = (cos, sin)(s * 10000^(-p/32)).  grid (256,5) x 256.
// ---------------------------------------------------------------------------
__global__ __launch_bounds__(256) void prep_kernel(
    const float* __restrict__ x, const float* __restrict__ wq,
    const float* __restrict__ wk, const float* __restrict__ wv,
    short* __restrict__ xb, short* __restrict__ wqb,
    short* __restrict__ wkb, short* __restrict__ wvb,
    float2* __restrict__ tab) {
  const int y = blockIdx.y;
  if (y == 4) {
    int i = blockIdx.x * 256 + threadIdx.x;  // 65536 = 2048*32 exactly
    int s = i >> 5, p = i & 31;
    float inv_freq = __expf(-0.28782313662425575f * (float)p);
    float ang = (float)s * inv_freq;
    float sn, c;
    sincosf(ang, &sn, &c);  // accurate; one-time cost
    tab[i] = make_float2(c, sn);
    return;
  }
  const float* src = (y == 0) ? x : (y == 1) ? wq : (y == 2) ? wk : wv;
  short* dst = (y == 0) ? xb : (y == 1) ? wqb : (y == 2) ? wkb : wvb;
  const int n4 = ((y == 0) ? NTOK * D_MODEL : D_MODEL * D_MODEL) >> 2;
  for (int i = blockIdx.x * 256 + threadIdx.x; i < n4; i += gridDim.x * 256) {
    float4 v = ((const float4*)src)[i];
    short4 o;
    o.x = b16(v.x); o.y = b16(v.y); o.z = b16(v.z); o.w = b16(v.w);
    ((short4*)dst)[i] = o;
  }
}

// ---------------------------------------------------------------------------
// QKV + RoPE (unchanged from R24): LDS-staged 128x128 tile, BK=64, T2 XOR
// swizzle paired for global_load_lds. Epilogue: fragment-packed Q/K/V.
// ---------------------------------------------------------------------------
__global__ __launch_bounds__(256) void qkv_rope_kernel(
    const short* __restrict__ xb,
    const short* __restrict__ Wqb, const short* __restrict__ Wkb,
    const short* __restrict__ Wvb,
    const float2* __restrict__ ropetab,
    short* __restrict__ qws, short* __restrict__ kws, short* __restrict__ vtws) {
  __shared__ __align__(16) short SM[4 * 64 * 72];  // 36KB; staging uses 32KB
  short* As = SM;              // [128][64] bf16, swizzled units
  short* Bs = SM + 128 * 64;

  const int tid = threadIdx.x;
  const int lane = tid & 63;
  const int wv = tid >> 6;
  const int col = lane & 15, quad = lane >> 4;
  const int half = lane >> 5, l31 = lane & 31;
  const int wr = wv >> 1, wc = wv & 1;
  const int gemm = blockIdx.y;
  const int bm = blockIdx.x >> 3;
  const int bn = blockIdx.x & 7;
  const short* W = (gemm == 0) ? Wqb : (gemm == 1) ? Wkb : Wvb;

  const int srow8 = lane >> 3;                    // 0..7
  const int scolsw = ((lane & 7) ^ srow8) * 8;    // swizzled source col
  const short* gAa[4]; short* lAa[4];
  const short* gBa[4]; short* lBa[4];
#pragma unroll
  for (int g = 0; g < 2; ++g)
#pragma unroll
    for (int j = 0; j < 2; ++j) {
      const int idx = g * 2 + j;
      const int r0 = g * 64 + wv * 16 + j * 8;
      gAa[idx] = xb + (size_t)(bm * 128 + r0 + srow8) * D_MODEL + scolsw;
      lAa[idx] = As + r0 * 64;
      gBa[idx] = W + (size_t)(bn * 128 + r0 + srow8) * D_MODEL + scolsw;
      lBa[idx] = Bs + r0 * 64;
    }

  floatx4 acc[4][4];
#pragma unroll
  for (int i = 0; i < 4; ++i)
#pragma unroll
    for (int j = 0; j < 4; ++j) acc[i][j] = (floatx4){0.f, 0.f, 0.f, 0.f};

  const int arow = wr * 64;  // this wave's A row base (mult of 8)
  const int brow = wc * 64;

  for (int k0 = 0; k0 < D_MODEL; k0 += 64) {
    __syncthreads();
#pragma unroll
    for (int i = 0; i < 4; ++i) gl2lds16(gAa[i] + k0, lAa[i]);
#pragma unroll
    for (int i = 0; i < 4; ++i) gl2lds16(gBa[i] + k0, lBa[i]);
    __syncthreads();
#pragma unroll
    for (int kk = 0; kk < 2; ++kk) {
      bf16x8 a[4], b[4];
      const int usel = (kk * 4 + quad) ^ (col & 7);  // swizzled 16B unit
#pragma unroll
      for (int mt = 0; mt < 4; ++mt)
        a[mt] = ld_frag(&As[(arow + mt * 16 + col) * 64 + usel * 8]);
#pragma unroll
      for (int nt = 0; nt < 4; ++nt)
        b[nt] = ld_frag(&Bs[(brow + nt * 16 + col) * 64 + usel * 8]);
#pragma unroll
      for (int mt = 0; mt < 4; ++mt)
#pragma unroll
        for (int nt = 0; nt < 4; ++nt)
          acc[mt][nt] = MFMA16(a[mt], b[nt], acc[mt][nt]);
    }
  }
  __syncthreads();  // staging region about to be reused as epilogue buffer

  // ---- epilogue (per-wave 64x64 tile) -------------------------------------
  const int tm = bm * 2 + wr;   // 0..63
  const int tn = bn * 2 + wc;   // 0..15 (= head)
  short* Ep = &SM[wv * 64 * 72];
  const int mbase = tm * 64;
  const int bb = mbase >> 11;
  const int s0 = mbase & (S_LEN - 1);

  if (gemm == 2) {
    // Ep[d][s] (d = nl 0..63, s = ml 0..63), stride 72
#pragma unroll
    for (int mt = 0; mt < 4; ++mt)
#pragma unroll
      for (int nt = 0; nt < 4; ++nt) {
        int nl = nt * 16 + col;
#pragma unroll
        for (int r = 0; r < 4; ++r)
          Ep[nl * 72 + mt * 16 + quad * 4 + r] = b16(acc[mt][nt][r]);
      }
    // fragment-packed V store: lane l <-> [d = dt*32+l31][keys kc*16+half*8..]
    short* vb2 = vtws + (size_t)(bb * NHEAD + tn) * S_LEN * DHEAD;
    const int vtile = s0 >> 6;  // 64-key tile index (0..31)
#pragma unroll
    for (int dt = 0; dt < 2; ++dt) {
      const int4* src = (const int4*)&Ep[(dt * 32 + l31) * 72];
      int4* dst = (int4*)(vb2 + (size_t)(vtile * 8 + dt) * 512);
#pragma unroll
      for (int kc = 0; kc < 4; ++kc)
        dst[kc * 2 * 64 + lane] = src[kc * 2 + half];
    }
  } else {
    short* outp = (gemm == 0) ? qws : kws;
    const float qscale = (gemm == 0) ? QSCALE_LOG2E : 1.0f;
    // Ep[token][d] (token = ml 0..63, d = nl 0..63), stride 72
#pragma unroll
    for (int nt = 0; nt < 4; ++nt) {
      int nl = nt * 16 + col;
      const float2* tp = ropetab + (nl >> 1);
#pragma unroll
      for (int mt = 0; mt < 4; ++mt)
#pragma unroll
        for (int r = 0; r < 4; ++r) {
          int ml = mt * 16 + quad * 4 + r;
          float2 cs = tp[(size_t)(s0 + ml) * 32];
          float val = acc[mt][nt][r];
          float partner = __shfl_xor(val, 1);
          float o = ((nl & 1) == 0) ? (val * cs.x - partner * cs.y)
                                    : (partner * cs.y + val * cs.x);
          Ep[ml * 72 + nl] = b16(o * qscale);
        }
    }
    // fragment-packed Q/K store: lane l <-> [token = g2*32+l31][d kc*16+half*8..]
    short* ob2 = outp + (size_t)(bb * NHEAD + tn) * S_LEN * DHEAD;
    const int kgrp0 = s0 >> 5;  // 32-token group index (0..63)
#pragma unroll
    for (int g2 = 0; g2 < 2; ++g2) {
      const int4* src = (const int4*)&Ep[(g2 * 32 + l31) * 72];
      int4* dst = (int4*)(ob2 + (size_t)((kgrp0 + g2) * 4) * 512);
#pragma unroll
      for (int kc = 0; kc < 4; ++kc)
        dst[kc * 64 + lane] = src[kc * 2 + half];
    }
  }
}

// ---------------------------------------------------------------------------
// Split-K flash attention (R27, benched 51.4us): fragment-packed lane-linear
// Q/K/V loads; exp2 softmax; in-register P via cvt_pk + permlane32_swap;
// single K buffer with in-place prefetch; parallel 4-way merge;
// shuffle-skip defer-max; max3 tree. grid 2048 x 256.
// ---------------------------------------------------------------------------
__global__ __launch_bounds__(256) void attn_kernel(
    const short* __restrict__ qws, const short* __restrict__ kws,
    const short* __restrict__ vtws, short* __restrict__ att) {
  const int tid = threadIdx.x;
  const int wv = tid >> 6;
  const int lane = tid & 63;
  const int half = lane >> 5, l31 = lane & 31;
  const int bh = blockIdx.x & 31;          // consecutive blocks -> different
  const int b = bh >> 4, h = bh & 15;      // (b,h): same (b,h) lands on the
  const int qt = 63 - (blockIdx.x >> 5);   // same XCD; big tiles first
  const int q0 = qt * 32;

  __shared__ float ml[2][4][32];      // [0]=m, [1]=l  per wave per q
  __shared__ float Obuf[4][64][33];   // per-wave scaled O^T partials (34KB)

  const short* qbase = qws + (size_t)(b * NHEAD + h) * S_LEN * DHEAD;
  const short* kbase = kws + (size_t)(b * NHEAD + h) * S_LEN * DHEAD;
  const short* vbase = vtws + (size_t)(b * NHEAD + h) * S_LEN * DHEAD;

  bf16x8 qf[4];
#pragma unroll
  for (int kc = 0; kc < 4; ++kc)
    qf[kc] = ld_frag(qbase + (size_t)(qt * 4 + kc) * 512 + lane * 8);

  float m_i = NEG_SENTINEL, l_i = 0.f;   // log2-domain running max / sum
  floatx16 ot[2] = {};  // O^T: d = dt*32+(rg&3)+8*(rg>>2)+4*half, q = l31

  const int nit = (q0 + 32 + 63) >> 6;  // total 64-key tiles

  bf16x8 kfA[2][4];  // single K buffer; in-place prefetch after QK^T
  auto loadK = [&](int tkt) {
#pragma unroll
    for (int s = 0; s < 2; ++s) {
      if (tkt + s * 32 <= q0 + 31) {  // wave-uniform validity
        const short* kr = kbase + (size_t)(((tkt >> 5) + s) * 4) * 512 + lane * 8;
#pragma unroll
        for (int kc = 0; kc < 4; ++kc) kfA[s][kc] = ld_frag(kr + kc * 512);
      }
    }
  };

  int it = wv;
  if (it < nit) loadK(it * 64);  // prologue

  for (; it < nit; it += 4) {
    const int kt = it * 64;
    // --- V loads first: lane-linear packed frags, overlap softmax chain
    bf16x8 vf[4][2];
    {
      const short* vr = vbase + (size_t)(kt >> 6) * 8 * 512 + lane * 8;
#pragma unroll
      for (int kc = 0; kc < 4; ++kc)
#pragma unroll
        for (int dt = 0; dt < 2; ++dt)
          vf[kc][dt] = ld_frag(vr + (size_t)(kc * 2 + dt) * 512);
    }
    // --- scores from the prefetched K registers (already x log2e)
    floatx16 sc[2];
#pragma unroll
    for (int s = 0; s < 2; ++s) {
      if (kt + s * 32 <= q0 + 31) {
        floatx16 a = {};
#pragma unroll
        for (int kc = 0; kc < 4; ++kc) a = MFMA32(kfA[s][kc], qf[kc], a);
        sc[s] = a;
      } else {
#pragma unroll
        for (int rg = 0; rg < 16; ++rg) sc[s][rg] = NEG_SENTINEL;
      }
    }
    // --- kfA dead after the score MFMAs: prefetch next tile's K in place
    if (it + 4 < nit) loadK((it + 4) * 64);

    // --- causal mask (wave-uniform skip for full tiles)
    if (kt + 63 > q0) {
      const int lim = q0 + l31 - kt;  // key-rel <= lim is valid
#pragma unroll
      for (int s = 0; s < 2; ++s)
#pragma unroll
        for (int rg = 0; rg < 16; ++rg) {
          int rel = s * 32 + (rg & 3) + 8 * (rg >> 2) + 4 * half;
          if (rel > lim) sc[s][rg] = NEG_SENTINEL;
        }
    }
    // --- per-half row max via max3 triples (depth 4, ~17 instrs)
    float u[11];
#pragma unroll
    for (int j = 0; j < 10; ++j)
      u[j] = max3f(((const float*)&sc[0])[3 * j],
                   ((const float*)&sc[0])[3 * j + 1],
                   ((const float*)&sc[0])[3 * j + 2]);
    u[10] = fmaxf(((const float*)&sc[0])[30], ((const float*)&sc[0])[31]);
    float w0 = max3f(u[0], u[1], u[2]);
    float w1 = max3f(u[3], u[4], u[5]);
    float w2 = max3f(u[6], u[7], u[8]);
    float w3 = fmaxf(u[9], u[10]);
    float rm = fmaxf(fmaxf(w0, w1), fmaxf(w2, w3));  // this half's max

    // --- defer-max: cross-half shuffle only when a rescale is needed.
    // __all over 64 lanes covers both halves => equivalent to the full-max
    // condition; m_i update inside uses the true cross-half max.
    if (!__all(rm <= m_i + 8.0f)) {
      float rmf = fmaxf(rm, __shfl_xor(rm, 32));
      float mnew = fmaxf(m_i, rmf);
      float alpha = exp2f(m_i - mnew);
      m_i = mnew;
      l_i *= alpha;
#pragma unroll
      for (int dt = 0; dt < 2; ++dt)
#pragma unroll
        for (int rg = 0; rg < 16; ++rg) ot[dt][rg] *= alpha;
    }

    // --- P = exp2(S - m), packed to bf16-pairs in registers (no LDS)
    unsigned pw[8][2];
    float rsp[8];
#pragma unroll
    for (int s = 0; s < 2; ++s)
#pragma unroll
      for (int g = 0; g < 4; ++g) {
        float p0 = exp2f(sc[s][4 * g + 0] - m_i);
        float p1 = exp2f(sc[s][4 * g + 1] - m_i);
        float p2 = exp2f(sc[s][4 * g + 2] - m_i);
        float p3 = exp2f(sc[s][4 * g + 3] - m_i);
        rsp[s * 4 + g] = (p0 + p1) + (p2 + p3);
        pw[s * 4 + g][0] = pk2(p0, p1);
        pw[s * 4 + g][1] = pk2(p2, p3);
      }
    float rs = ((rsp[0] + rsp[1]) + (rsp[2] + rsp[3])) +
               ((rsp[4] + rsp[5]) + (rsp[6] + rsp[7]));
    rs += __shfl_xor(rs, 32);
    l_i += rs;

    // --- PV: permlane32_swap assembles B-fragments in-register
#pragma unroll
    for (int kc = 0; kc < 4; ++kc) {
      intx2 s01 = __builtin_amdgcn_permlane32_swap(
          (int)pw[2 * kc][0], (int)pw[2 * kc + 1][0], false, false);
      intx2 s23 = __builtin_amdgcn_permlane32_swap(
          (int)pw[2 * kc][1], (int)pw[2 * kc + 1][1], false, false);
      union { unsigned u[4]; bf16x8 f; } fr;
      fr.u[0] = (unsigned)s01[0]; fr.u[1] = (unsigned)s23[0];
      fr.u[2] = (unsigned)s01[1]; fr.u[3] = (unsigned)s23[1];
#pragma unroll
      for (int dt = 0; dt < 2; ++dt)
        ot[dt] = MFMA32(vf[kc][dt], fr.f, ot[dt]);
    }
  }

  // ---- parallel block merge (log2 domain): 2 barriers, no serial rounds --
  ml[0][wv][l31] = m_i;
  ml[1][wv][l31] = l_i;
  __syncthreads();
  float m0 = ml[0][0][l31], m1 = ml[0][1][l31];
  float m2 = ml[0][2][l31], m3 = ml[0][3][l31];
  float mtot = fmaxf(fmaxf(m0, m1), fmaxf(m2, m3));
  float sw = exp2f(m_i - mtot);  // idle wave: 0

#pragma unroll
  for (int dt = 0; dt < 2; ++dt)
#pragma unroll
    for (int rg = 0; rg < 16; ++rg) {
      int d = dt * 32 + (rg & 3) + 8 * (rg >> 2) + 4 * half;
      Obuf[wv][d][l31] = ot[dt][rg] * sw;
    }
  __syncthreads();

  // ---- final normalize + coalesced store (128B per q-row) ---------------
  const int q = tid >> 3;            // 0..31
  const int d0 = (tid & 7) * 8;      // 0,8,..,56
  float mm0 = ml[0][0][q], mm1 = ml[0][1][q], mm2 = ml[0][2][q], mm3 = ml[0][3][q];
  float mt2 = fmaxf(fmaxf(mm0, mm1), fmaxf(mm2, mm3));
  float lt = ml[1][0][q] * exp2f(mm0 - mt2) + ml[1][1][q] * exp2f(mm1 - mt2) +
             ml[1][2][q] * exp2f(mm2 - mt2) + ml[1][3][q] * exp2f(mm3 - mt2);
  float inv = 1.0f / lt;  // lt >= 1
  union { bf16x8 hh; int4 i4; } cv;
#pragma unroll
  for (int i = 0; i < 8; ++i) {
    float v = ((Obuf[0][d0 + i][q] + Obuf[1][d0 + i][q]) +
               (Obuf[2][d0 + i][q] + Obuf[3][d0 + i][q]));
    cv.hh[i] = (__bf16)(v * inv);
  }
  int4* dst = (int4*)(att + (size_t)(b * S_LEN + q0 + q) * D_MODEL + h * DHEAD + d0);
  *dst = cv.i4;
}

// ---------------------------------------------------------------------------
// Output projection (unchanged from R26): BK=64, T2 XOR swizzle; A via
// global_load_lds w/ inverse-permuted source; B (fp32 Wo) reg-staged with
// swizzled ds_write. 128x64 tiles, 512 blocks = 2 blocks/CU.
// ---------------------------------------------------------------------------
__global__ __launch_bounds__(256) void out_gemm_kernel(
    const short* __restrict__ att, const float* __restrict__ Wo,
    float* __restrict__ out) {
  __shared__ __align__(16) short As[128 * 64];  // 16KB, swizzled units
  __shared__ __align__(16) short Bs[64 * 64];   // 8KB, swizzled units

  const int tid = threadIdx.x;
  const int lane = tid & 63;
  const int wv = tid >> 6;
  const int col = lane & 15, quad = lane >> 4;
  const int wr = wv >> 1, wc = wv & 1;
  const int bm = blockIdx.x >> 4;   // 32 M-tiles of 128
  const int bn = blockIdx.x & 15;   // 16 N-tiles of 64

  const int srow8 = lane >> 3;
  const int scolsw = ((lane & 7) ^ srow8) * 8;    // swizzled source col
  const short* gAa[4]; short* lAa[4];
#pragma unroll
  for (int g = 0; g < 2; ++g)
#pragma unroll
    for (int j = 0; j < 2; ++j) {
      const int idx = g * 2 + j;
      const int r0 = g * 64 + wv * 16 + j * 8;
      gAa[idx] = att + (size_t)(bm * 128 + r0 + srow8) * D_MODEL + scolsw;
      lAa[idx] = As + r0 * 64;
    }

  const int browB = tid >> 2;
  const int bc0 = (tid & 3) * 16;
  const float* gBf = Wo + (size_t)(bn * 64 + browB) * D_MODEL + bc0;
  short* lBw0 = Bs + browB * 64 + (((tid & 3) * 2) ^ (browB & 7)) * 8;
  short* lBw1 = Bs + browB * 64 + (((tid & 3) * 2 + 1) ^ (browB & 7)) * 8;

  floatx4 acc[4][2];
#pragma unroll
  for (int i = 0; i < 4; ++i)
#pragma unroll
    for (int j = 0; j < 2; ++j) acc[i][j] = (floatx4){0.f, 0.f, 0.f, 0.f};

  const int arow = wr * 64;
  const int brow = wc * 32;

  for (int k0 = 0; k0 < D_MODEL; k0 += 64) {
    float4 w0 = *(const float4*)(gBf + k0);
    float4 w1 = *(const float4*)(gBf + k0 + 4);
    float4 w2 = *(const float4*)(gBf + k0 + 8);
    float4 w3 = *(const float4*)(gBf + k0 + 12);
    __syncthreads();  // prev iteration's LDS reads drained
#pragma unroll
    for (int i = 0; i < 4; ++i) gl2lds16(gAa[i] + k0, lAa[i]);
    union { unsigned u[4]; int4 i4; } b0, b1;
    b0.u[0] = pk2(w0.x, w0.y); b0.u[1] = pk2(w0.z, w0.w);
    b0.u[2] = pk2(w1.x, w1.y); b0.u[3] = pk2(w1.z, w1.w);
    b1.u[0] = pk2(w2.x, w2.y); b1.u[1] = pk2(w2.z, w2.w);
    b1.u[2] = pk2(w3.x, w3.y); b1.u[3] = pk2(w3.z, w3.w);
    *(int4*)lBw0 = b0.i4;
    *(int4*)lBw1 = b1.i4;
    __syncthreads();  // tile resident (vmcnt for gl2lds16, lgkm for ds_write)
#pragma unroll
    for (int kk = 0; kk < 2; ++kk) {
      bf16x8 a[4], b[2];
      const int usel = (kk * 4 + quad) ^ (col & 7);  // swizzled 16B unit
#pragma unroll
      for (int mt = 0; mt < 4; ++mt)
        a[mt] = ld_frag(&As[(arow + mt * 16 + col) * 64 + usel * 8]);
#pragma unroll
      for (int nt = 0; nt < 2; ++nt)
        b[nt] = ld_frag(&Bs[(brow + nt * 16 + col) * 64 + usel * 8]);
#pragma unroll
      for (int mt = 0; mt < 4; ++mt)
#pragma unroll
        for (int nt = 0; nt < 2; ++nt)
          acc[mt][nt] = MFMA16(a[mt], b[nt], acc[mt][nt]);
    }
  }

#pragma unroll
  for (int mt = 0; mt < 4; ++mt)
#pragma unroll
    for (int nt = 0; nt < 2; ++nt) {
      int n = bn * 64 + wc * 32 + nt * 16 + col;
#pragma unroll
      for (int r = 0; r < 4; ++r) {
        int m = bm * 128 + wr * 64 + mt * 16 + quad * 4 + r;
        out[(size_t)m * D_MODEL + n] = acc[mt][nt][r];
      }
    }
}

// ---------------------------------------------------------------------------
extern "C" void kernel_launch(void* const* d_in, const int* in_sizes, int n_in,
                              void* d_out, int out_size, void* d_ws, size_t ws_size,
                              hipStream_t stream) {
  const float* x  = (const float*)d_in[0];
  const float* Wq = (const float*)d_in[2];
  const float* Wk = (const float*)d_in[3];
  const float* Wv = (const float*)d_in[4];
  const float* Wo = (const float*)d_in[5];
  float* out = (float*)d_out;

  const size_t TENS = (size_t)NTOK * D_MODEL;
  const size_t WELEM = (size_t)D_MODEL * D_MODEL;

  short* qws  = (short*)d_out;
  short* xb   = (short*)d_out + TENS;
  short* kws  = (short*)d_ws;
  short* vtws = kws + TENS;
  short* attws = vtws + TENS;
  short* wqb = attws;
  short* wkb = wqb + WELEM;
  short* wvb = wkb + WELEM;
  float2* ropetab = (float2*)(wvb + WELEM);

  prep_kernel<<<dim3(256, 5), 256, 0, stream>>>(x, Wq, Wk, Wv, xb, wqb, wkb, wvb, ropetab);
  qkv_rope_kernel<<<dim3(256, 3), 256, 0, stream>>>(xb, wqb, wkb, wvb, ropetab, qws, kws, vtws);
  attn_kernel<<<dim3(2048), 256, 0, stream>>>(qws, kws, vtws, attws);
  out_gemm_kernel<<<dim3(512), 256, 0, stream>>>(attws, Wo, out);
}